// Round 11
// baseline (1019.874 us; speedup 1.0000x reference)
//
#include <hip/hip_runtime.h>

#define B_SZ   256
#define DIN    128
#define T_LEN  2000
#define K_SZ   64
#define TT     64
#define NTILE  32
#define ISTR   68   // Ibuf row stride: 272B -> float4-aligned, conflict-free scan reads

// ---- kernel A: transpose W[64][128] -> Wt[128][64] in d_ws (runs every launch; pure) ----
__global__ void transpose_w(const float* __restrict__ W, float* __restrict__ Wt) {
  const int idx = blockIdx.x * 256 + threadIdx.x;
  if (idx < K_SZ * DIN) {
    const int k = idx >> 7;
    const int d = idx & 127;
    Wt[d * K_SZ + k] = W[idx];
  }
}

// ---- 16 sequential LIF steps; all lanes compute (branch-free), lanes<16 store ----
__device__ __forceinline__ void scan16(const float* __restrict__ Ir, int c0, int tg,
                                       float bias_s, float alpha, float vth_s,
                                       float& V, float* __restrict__ outS,
                                       float* __restrict__ outV, int sk, bool active)
{
#pragma unroll
  for (int q = 0; q < 4; ++q) {
    const float4 iv = *(const float4*)&Ir[c0 + 4*q];
    float S0,S1,S2,S3, V0,V1,V2,V3;
    { const float Vp = fmaf(alpha, V, iv.x + bias_s); const bool sp = Vp > vth_s;
      V0 = sp ? (Vp - vth_s) : Vp; S0 = sp ? 1.0f : 0.0f; V = V0; }
    { const float Vp = fmaf(alpha, V, iv.y + bias_s); const bool sp = Vp > vth_s;
      V1 = sp ? (Vp - vth_s) : Vp; S1 = sp ? 1.0f : 0.0f; V = V1; }
    { const float Vp = fmaf(alpha, V, iv.z + bias_s); const bool sp = Vp > vth_s;
      V2 = sp ? (Vp - vth_s) : Vp; S2 = sp ? 1.0f : 0.0f; V = V2; }
    { const float Vp = fmaf(alpha, V, iv.w + bias_s); const bool sp = Vp > vth_s;
      V3 = sp ? (Vp - vth_s) : Vp; S3 = sp ? 1.0f : 0.0f; V = V3; }
    if (active) {
      *(float4*)&outS[(size_t)sk * T_LEN + tg + 4*q] = make_float4(S0, S1, S2, S3);
      *(float4*)&outV[(size_t)sk * T_LEN + tg + 4*q] = make_float4(V0, V1, V2, V3);
    }
  }
}

__global__ __launch_bounds__(256, 1)
void lif_fused(const float* __restrict__ x,
               const float* __restrict__ Wt,    // [d][k] in d_ws (from transpose_w)
               const float* __restrict__ bias,
               const float* __restrict__ vth,
               const float* __restrict__ tau,
               float* __restrict__ out)
{
  __shared__ __align__(16) float Ibuf[2][K_SZ * ISTR];   // 34 KB; rows wave-private -> NO barriers

  const int tid  = threadIdx.x;
  const int b    = blockIdx.x;
  const int wave = __builtin_amdgcn_readfirstlane(tid >> 6);  // force wave-uniform for s_load path
  const int lane = tid & 63;
  const int k0   = wave << 4;                  // this wave's 16 k's

  const int   sk     = k0 + (lane & 15);       // scan chain owned by lane (4x redundant compute)
  const float alpha  = expf(-1.0f / tau[sk]);
  const float vth_s  = vth[sk];
  const float bias_s = bias[sk];

  const float* xb   = x + (size_t)b * (DIN * T_LEN);
  float*       outS = out + (size_t)b * (K_SZ * T_LEN);
  float*       outV = outS + (size_t)B_SZ * K_SZ * T_LEN;

  const bool active = (lane < 16);
  float V = 0.0f;
  float acc[16];

#pragma unroll 1
  for (int tile = 0; tile < NTILE; ++tile) {
    const int t0 = tile * TT;
    int tcol = t0 + lane;
    if (tcol > T_LEN - 1) tcol = T_LEN - 1;    // clamped lanes' results never stored
    const float* xcol = xb + tcol;

#pragma unroll
    for (int i = 0; i < 16; ++i) acc[i] = 0.0f;

    // ---- GEMM: lane = t. x: coalesced global (L1-shared across waves).
    // W: wave-uniform const loads -> scalar pipe (SGPR operands to v_fmac). ----
#pragma unroll 4
    for (int d = 0; d < DIN; ++d) {
      const float xv = xcol[(size_t)d * T_LEN];
      const float* wp = Wt + d * K_SZ + k0;    // uniform address
      const float4 w0 = *(const float4*)(wp + 0);
      const float4 w1 = *(const float4*)(wp + 4);
      const float4 w2 = *(const float4*)(wp + 8);
      const float4 w3 = *(const float4*)(wp + 12);
      acc[0]  = fmaf(w0.x, xv, acc[0]);  acc[1]  = fmaf(w0.y, xv, acc[1]);
      acc[2]  = fmaf(w0.z, xv, acc[2]);  acc[3]  = fmaf(w0.w, xv, acc[3]);
      acc[4]  = fmaf(w1.x, xv, acc[4]);  acc[5]  = fmaf(w1.y, xv, acc[5]);
      acc[6]  = fmaf(w1.z, xv, acc[6]);  acc[7]  = fmaf(w1.w, xv, acc[7]);
      acc[8]  = fmaf(w2.x, xv, acc[8]);  acc[9]  = fmaf(w2.y, xv, acc[9]);
      acc[10] = fmaf(w2.z, xv, acc[10]); acc[11] = fmaf(w2.w, xv, acc[11]);
      acc[12] = fmaf(w3.x, xv, acc[12]); acc[13] = fmaf(w3.y, xv, acc[13]);
      acc[14] = fmaf(w3.z, xv, acc[14]); acc[15] = fmaf(w3.w, xv, acc[15]);
    }

    // ---- hand I to the scan via wave-private LDS rows (lane-stride-1, conflict-free) ----
    float* Iw = Ibuf[tile & 1];
#pragma unroll
    for (int kk = 0; kk < 16; ++kk)
      Iw[(k0 + kk) * ISTR + lane] = acc[kk];

    // ---- scan previous tile (same wave wrote it -> program-order LDS dep, no barrier) ----
    if (tile > 0) {
      const float* Ir = Ibuf[(tile - 1) & 1] + (size_t)sk * ISTR;
      const int   tp0 = (tile - 1) * TT;
      scan16(Ir,  0, tp0 +  0, bias_s, alpha, vth_s, V, outS, outV, sk, active);
      scan16(Ir, 16, tp0 + 16, bias_s, alpha, vth_s, V, outS, outV, sk, active);
      scan16(Ir, 32, tp0 + 32, bias_s, alpha, vth_s, V, outS, outV, sk, active);
      scan16(Ir, 48, tp0 + 48, bias_s, alpha, vth_s, V, outS, outV, sk, active);
    }
  }

  // ---- epilogue: tile 31 valid cols 0..15 = t 1984..1999 ----
  {
    const float* Ir = Ibuf[(NTILE - 1) & 1] + (size_t)sk * ISTR;
    scan16(Ir, 0, (NTILE - 1) * TT, bias_s, alpha, vth_s, V, outS, outV, sk, active);
  }
}

extern "C" void kernel_launch(void* const* d_in, const int* in_sizes, int n_in,
                              void* d_out, int out_size, void* d_ws, size_t ws_size,
                              hipStream_t stream) {
  const float* x    = (const float*)d_in[0];
  const float* W    = (const float*)d_in[1];
  const float* bias = (const float*)d_in[2];
  const float* vth  = (const float*)d_in[3];
  const float* tau  = (const float*)d_in[4];
  float* out        = (float*)d_out;
  float* Wt         = (float*)d_ws;           // 32 KB scratch for W^T

  transpose_w<<<dim3((K_SZ * DIN + 255) / 256), dim3(256), 0, stream>>>(W, Wt);
  lif_fused<<<dim3(B_SZ), dim3(256), 0, stream>>>(x, Wt, bias, vth, tau, out);
}

// Round 12
// 674.908 us; speedup vs baseline: 1.5111x; 1.5111x over previous
//
#include <hip/hip_runtime.h>

#define B_SZ   256
#define DIN    128
#define T_LEN  2000
#define K_SZ   64
#define TT     64
#define NTILE  32
#define ISTR   68   // Ibuf row stride: 272B -> float4-aligned scan reads, conflict-free

// ---- kernel A: transpose W[64][128] -> Wt[128][64] in d_ws (re-runs every launch; pure) ----
__global__ void transpose_w(const float* __restrict__ W, float* __restrict__ Wt) {
  const int idx = blockIdx.x * 256 + threadIdx.x;
  if (idx < K_SZ * DIN) {
    const int k = idx >> 7;
    const int d = idx & 127;
    Wt[d * K_SZ + k] = W[idx];
  }
}

// ---- x staging: wave w owns d-rows [32w,32w+32); lane l: row 32w+4q+(l>>4), col 4*(l&15) ----
__device__ __forceinline__ void stage_load(const float* __restrict__ xl, float4 (&st)[8]) {
#pragma unroll
  for (int q = 0; q < 8; ++q)
    st[q] = *(const float4*)(xl + (size_t)q * 4 * T_LEN);
}

__device__ __forceinline__ void stage_write(float* __restrict__ Xb, const float4 (&st)[8],
                                            int wave, int lane) {
  float* base = Xb + (wave * 32 + (lane >> 4)) * TT + (lane & 15) * 4;
#pragma unroll
  for (int q = 0; q < 8; ++q)
    *(float4*)(base + q * 4 * TT) = st[q];   // 1KB contiguous per instr, conflict-free
}

// ---- GEMM half: 64 d-steps. x: ds_read_b32 (lane=t, stride-1, free 2-way).
//      W: wave-uniform scalar loads (SGPR operands; proven scalarized in R11, VGPR=52). ----
__device__ __forceinline__ void gemm_half(const float* __restrict__ Xc,
                                          const float* __restrict__ Wt,
                                          int d0, int k0, int lane, float (&acc)[16]) {
#pragma unroll 4
  for (int dd = 0; dd < 64; ++dd) {
    const int d = d0 + dd;
    const float xv = Xc[d * TT + lane];
    const float* wp = Wt + d * K_SZ + k0;    // uniform address -> s_load
    const float4 w0 = *(const float4*)(wp + 0);
    const float4 w1 = *(const float4*)(wp + 4);
    const float4 w2 = *(const float4*)(wp + 8);
    const float4 w3 = *(const float4*)(wp + 12);
    acc[0]  = fmaf(w0.x, xv, acc[0]);  acc[1]  = fmaf(w0.y, xv, acc[1]);
    acc[2]  = fmaf(w0.z, xv, acc[2]);  acc[3]  = fmaf(w0.w, xv, acc[3]);
    acc[4]  = fmaf(w1.x, xv, acc[4]);  acc[5]  = fmaf(w1.y, xv, acc[5]);
    acc[6]  = fmaf(w1.z, xv, acc[6]);  acc[7]  = fmaf(w1.w, xv, acc[7]);
    acc[8]  = fmaf(w2.x, xv, acc[8]);  acc[9]  = fmaf(w2.y, xv, acc[9]);
    acc[10] = fmaf(w2.z, xv, acc[10]); acc[11] = fmaf(w2.w, xv, acc[11]);
    acc[12] = fmaf(w3.x, xv, acc[12]); acc[13] = fmaf(w3.y, xv, acc[13]);
    acc[14] = fmaf(w3.z, xv, acc[14]); acc[15] = fmaf(w3.w, xv, acc[15]);
  }
}

// ---- 16 sequential LIF steps; all lanes compute (branch-free), lanes<16 store ----
__device__ __forceinline__ void scan16(const float* __restrict__ Ir, int c0, int tg,
                                       float bias_s, float alpha, float vth_s,
                                       float& V, float* __restrict__ outS,
                                       float* __restrict__ outV, int sk, bool active)
{
#pragma unroll
  for (int q = 0; q < 4; ++q) {
    const float4 iv = *(const float4*)&Ir[c0 + 4*q];
    float S0,S1,S2,S3, V0,V1,V2,V3;
    { const float Vp = fmaf(alpha, V, iv.x + bias_s); const bool sp = Vp > vth_s;
      V0 = sp ? (Vp - vth_s) : Vp; S0 = sp ? 1.0f : 0.0f; V = V0; }
    { const float Vp = fmaf(alpha, V, iv.y + bias_s); const bool sp = Vp > vth_s;
      V1 = sp ? (Vp - vth_s) : Vp; S1 = sp ? 1.0f : 0.0f; V = V1; }
    { const float Vp = fmaf(alpha, V, iv.z + bias_s); const bool sp = Vp > vth_s;
      V2 = sp ? (Vp - vth_s) : Vp; S2 = sp ? 1.0f : 0.0f; V = V2; }
    { const float Vp = fmaf(alpha, V, iv.w + bias_s); const bool sp = Vp > vth_s;
      V3 = sp ? (Vp - vth_s) : Vp; S3 = sp ? 1.0f : 0.0f; V = V3; }
    if (active) {
      *(float4*)&outS[(size_t)sk * T_LEN + tg + 4*q] = make_float4(S0, S1, S2, S3);
      *(float4*)&outV[(size_t)sk * T_LEN + tg + 4*q] = make_float4(V0, V1, V2, V3);
    }
  }
}

__global__ __launch_bounds__(256, 1)
void lif_fused(const float* __restrict__ x,
               const float* __restrict__ Wt,    // [d][k] from transpose_w (d_ws)
               const float* __restrict__ bias,
               const float* __restrict__ vth,
               const float* __restrict__ tau,
               float* __restrict__ out)
{
  __shared__ __align__(16) float Xt[2][DIN * TT];       // 64 KB [d][t] double-buffered
  __shared__ __align__(16) float Ibuf[2][K_SZ * ISTR];  // 34 KB [k][t]; rows wave-private

  const int tid  = threadIdx.x;
  const int b    = blockIdx.x;
  const int wave = __builtin_amdgcn_readfirstlane(tid >> 6);  // wave-uniform for s_load path
  const int lane = tid & 63;
  const int k0   = wave << 4;                  // this wave's 16 contiguous k's

  const int   sk     = k0 + (lane & 15);       // scan chain owned by lane (4x redundant compute)
  const float alpha  = expf(-1.0f / tau[sk]);
  const float vth_s  = vth[sk];
  const float bias_s = bias[sk];

  const float* xb   = x + (size_t)b * (DIN * T_LEN);
  float*       outS = out + (size_t)b * (K_SZ * T_LEN);
  float*       outV = outS + (size_t)B_SZ * K_SZ * T_LEN;

  // per-lane global stage base: row = 32*wave + (lane>>4), col = (lane&15)*4
  const float* xl = xb + (size_t)(32 * wave + (lane >> 4)) * T_LEN + (lane & 15) * 4;

  const bool active = (lane < 16);
  float V = 0.0f;
  float acc[16];
  float4 st[8];

  // ---------------- prologue: stage tile 0 ----------------
  stage_load(xl + 0, st);
  stage_write(Xt[0], st, wave, lane);
  __syncthreads();

  // ---------------- tile 0: GEMM only ----------------
  {
    stage_load(xl + 64, st);                 // tile 1 (early issue)
#pragma unroll
    for (int i = 0; i < 16; ++i) acc[i] = 0.0f;
    gemm_half(Xt[0], Wt, 0, k0, lane, acc);
    stage_write(Xt[1], st, wave, lane);      // late write: ~full gemm-half of latency cover
    gemm_half(Xt[0], Wt, 64, k0, lane, acc);
#pragma unroll
    for (int kk = 0; kk < 16; ++kk)
      Ibuf[0][(k0 + kk) * ISTR + lane] = acc[kk];
    __syncthreads();
  }

  // ---------------- tiles 1..31: GEMM(tile) || scan(tile-1) ----------------
#pragma unroll 1
  for (int tile = 1; tile < NTILE; ++tile) {
    const int cur = tile & 1;
    const float* Xc = Xt[cur];
    float*       Iw = Ibuf[cur];
    const float* Ir = Ibuf[cur ^ 1] + (size_t)sk * ISTR;
    const int   tp0 = (tile - 1) * 64;
    const bool  has_next = (tile < NTILE - 1);
    const int  st0n = (tile + 1 == NTILE - 1) ? (T_LEN - TT) : (tile + 1) * 64; // tile31 staged from 1936

    if (has_next) stage_load(xl + st0n, st);
#pragma unroll
    for (int i = 0; i < 16; ++i) acc[i] = 0.0f;

    gemm_half(Xc, Wt, 0, k0, lane, acc);
    scan16(Ir,  0, tp0 +  0, bias_s, alpha, vth_s, V, outS, outV, sk, active);
    scan16(Ir, 16, tp0 + 16, bias_s, alpha, vth_s, V, outS, outV, sk, active);
    if (has_next) stage_write(Xt[cur ^ 1], st, wave, lane);
    gemm_half(Xc, Wt, 64, k0, lane, acc);
    scan16(Ir, 32, tp0 + 32, bias_s, alpha, vth_s, V, outS, outV, sk, active);
    scan16(Ir, 48, tp0 + 48, bias_s, alpha, vth_s, V, outS, outV, sk, active);
#pragma unroll
    for (int kk = 0; kk < 16; ++kk)
      Iw[(k0 + kk) * ISTR + lane] = acc[kk];
    if (has_next) __syncthreads();           // protect Xt[next]; Ibuf rows are wave-private
  }

  // ---------------- epilogue: tile 31 cols 48..63 = t 1984..1999 ----------------
  {
    const float* Ir = Ibuf[1] + (size_t)sk * ISTR;   // (NTILE-1)&1 == 1
    scan16(Ir, 48, 1984, bias_s, alpha, vth_s, V, outS, outV, sk, active);
  }
}

extern "C" void kernel_launch(void* const* d_in, const int* in_sizes, int n_in,
                              void* d_out, int out_size, void* d_ws, size_t ws_size,
                              hipStream_t stream) {
  const float* x    = (const float*)d_in[0];
  const float* W    = (const float*)d_in[1];
  const float* bias = (const float*)d_in[2];
  const float* vth  = (const float*)d_in[3];
  const float* tau  = (const float*)d_in[4];
  float* out        = (float*)d_out;
  float* Wt         = (float*)d_ws;          // 32 KB scratch for W^T

  transpose_w<<<dim3((K_SZ * DIN + 255) / 256), dim3(256), 0, stream>>>(W, Wt);
  lif_fused<<<dim3(B_SZ), dim3(256), 0, stream>>>(x, Wt, bias, vth, tau, out);
}